// Round 2
// baseline (1639.194 us; speedup 1.0000x reference)
//
#include <hip/hip_runtime.h>

#define NU 50000
#define NI 70000
#define NT 120000
#define DD 128
#define SLOPE 0.5f

__device__ __forceinline__ float lrelu(float x) { return x >= 0.f ? x : SLOPE * x; }

// C[n,128] = act(A[n,128] @ B[128,128]); 128 rows/block, 256 threads.
template<bool LEAKY>
__global__ __launch_bounds__(256)
void gemm_n128(const float* __restrict__ A, const float* __restrict__ Bg,
               float* __restrict__ C, int n) {
  __shared__ float Bs[128][128];
  int tid = threadIdx.x;
#pragma unroll
  for (int i = 0; i < 16; ++i)
    ((float4*)Bs)[tid + i * 256] = ((const float4*)Bg)[tid + i * 256];
  __syncthreads();

  int rg = tid >> 3;  // 0..31
  int cg = tid & 7;   // 0..7
  int rbase = blockIdx.x * 128 + rg * 4;

  float acc[4][16];
#pragma unroll
  for (int i = 0; i < 4; ++i)
#pragma unroll
    for (int j = 0; j < 16; ++j) acc[i][j] = 0.f;

  for (int k4 = 0; k4 < 128; k4 += 4) {
    float a[4][4];
#pragma unroll
    for (int i = 0; i < 4; ++i) {
      int r = rbase + i;
      float4 t = make_float4(0.f, 0.f, 0.f, 0.f);
      if (r < n) t = *(const float4*)(A + (size_t)r * DD + k4);
      a[i][0] = t.x; a[i][1] = t.y; a[i][2] = t.z; a[i][3] = t.w;
    }
#pragma unroll
    for (int kk = 0; kk < 4; ++kk) {
      float b[16];
#pragma unroll
      for (int jj = 0; jj < 4; ++jj)
        *(float4*)&b[jj * 4] = *(const float4*)&Bs[k4 + kk][cg * 4 + jj * 32];
#pragma unroll
      for (int i = 0; i < 4; ++i) {
        float av = a[i][kk];
#pragma unroll
        for (int j = 0; j < 16; ++j)
          acc[i][j] = fmaf(av, b[j], acc[i][j]);
      }
    }
  }

#pragma unroll
  for (int i = 0; i < 4; ++i) {
    int r = rbase + i;
    if (r < n) {
#pragma unroll
      for (int jj = 0; jj < 4; ++jj) {
        float x0 = acc[i][jj * 4 + 0], x1 = acc[i][jj * 4 + 1];
        float x2 = acc[i][jj * 4 + 2], x3 = acc[i][jj * 4 + 3];
        if (LEAKY) { x0 = lrelu(x0); x1 = lrelu(x1); x2 = lrelu(x2); x3 = lrelu(x3); }
        float4 o; o.x = x0; o.y = x1; o.z = x2; o.w = x3;
        *(float4*)(C + (size_t)r * DD + cg * 4 + jj * 32) = o;
      }
    }
  }
}

// out[128,128] += A[n,128]^T @ B[n,128] over this block's row chunk (atomic).
__global__ __launch_bounds__(256)
void gemm_tn_atomic(const float* __restrict__ A, const float* __restrict__ B,
                    float* __restrict__ out, int n, int chunk) {
  __shared__ float As[8][128];
  __shared__ float Bs[8][128];
  int tid = threadIdx.x;
  int ty = tid >> 4, tx = tid & 15;
  float acc[8][8];
#pragma unroll
  for (int i = 0; i < 8; ++i)
#pragma unroll
    for (int j = 0; j < 8; ++j) acc[i][j] = 0.f;

  int r0 = blockIdx.x * chunk;
  int r1 = min(r0 + chunk, n);
  int rr = tid >> 5;
  int cc = (tid & 31) * 4;

  for (int rb = r0; rb < r1; rb += 8) {
    int gr = rb + rr;
    float4 av = make_float4(0.f, 0.f, 0.f, 0.f);
    float4 bv = make_float4(0.f, 0.f, 0.f, 0.f);
    if (gr < r1) {
      av = *(const float4*)(A + (size_t)gr * DD + cc);
      bv = *(const float4*)(B + (size_t)gr * DD + cc);
    }
    __syncthreads();
    *(float4*)&As[rr][cc] = av;
    *(float4*)&Bs[rr][cc] = bv;
    __syncthreads();
#pragma unroll
    for (int r2 = 0; r2 < 8; ++r2) {
      float a[8], b[8];
      *(float4*)&a[0] = *(const float4*)&As[r2][ty * 8];
      *(float4*)&a[4] = *(const float4*)&As[r2][ty * 8 + 4];
      *(float4*)&b[0] = *(const float4*)&Bs[r2][tx * 4];
      *(float4*)&b[4] = *(const float4*)&Bs[r2][tx * 4 + 64];
#pragma unroll
      for (int i = 0; i < 8; ++i)
#pragma unroll
        for (int j = 0; j < 8; ++j)
          acc[i][j] = fmaf(a[i], b[j], acc[i][j]);
    }
  }

#pragma unroll
  for (int i = 0; i < 8; ++i) {
    int h = ty * 8 + i;
#pragma unroll
    for (int j = 0; j < 8; ++j) {
      int d = tx * 4 + (j < 4 ? j : 64 + (j - 4));
      atomicAdd(out + h * DD + d, acc[i][j]);
    }
  }
}

// out[128,128] = leaky(V @ lat) + lat ; grid = 16 blocks x 256 threads
__global__ __launch_bounds__(256)
void vgemm_res(const float* __restrict__ V, const float* __restrict__ lat,
               float* __restrict__ out) {
  int row = blockIdx.x * 8 + (threadIdx.x >> 5);
  int c4 = (threadIdx.x & 31) * 4;
  float4 acc = make_float4(0.f, 0.f, 0.f, 0.f);
  for (int k = 0; k < 128; ++k) {
    float v = V[row * 128 + k];
    float4 l = *(const float4*)(lat + k * 128 + c4);
    acc.x = fmaf(v, l.x, acc.x);
    acc.y = fmaf(v, l.y, acc.y);
    acc.z = fmaf(v, l.z, acc.z);
    acc.w = fmaf(v, l.w, acc.w);
  }
  float4 r = *(const float4*)(lat + row * 128 + c4);
  float4 o;
  o.x = lrelu(acc.x) + r.x;
  o.y = lrelu(acc.y) + r.y;
  o.z = lrelu(acc.z) + r.z;
  o.w = lrelu(acc.w) + r.w;
  *(float4*)(out + row * 128 + c4) = o;
}

// out[rows[e],:] += vals[e] * prev[cols[e],:]  (2 edges per 256-thread block)
__global__ __launch_bounds__(256)
void spmm_k(const int* __restrict__ rows, const int* __restrict__ cols,
            const float* __restrict__ vals, const float* __restrict__ prev,
            float* __restrict__ out, int E) {
  int e = blockIdx.x * 2 + (threadIdx.x >> 7);
  if (e >= E) return;
  int t = threadIdx.x & 127;
  int r = rows[e];
  int c = cols[e];
  float v = vals[e];
  atomicAdd(out + (size_t)r * DD + t, v * prev[(size_t)c * DD + t]);
}

__global__ __launch_bounds__(256)
void leaky_k(float* __restrict__ p, int n4) {
  int i = blockIdx.x * blockDim.x + threadIdx.x;
  int stride = gridDim.x * blockDim.x;
  for (; i < n4; i += stride) {
    float4 v = ((float4*)p)[i];
    v.x = lrelu(v.x); v.y = lrelu(v.y); v.z = lrelu(v.z); v.w = lrelu(v.w);
    ((float4*)p)[i] = v;
  }
}

// prev = g + h   (layer output, no residual — matches reference lats.append(tem+hyp))
__global__ __launch_bounds__(256)
void set2_k(float* __restrict__ prev, const float* __restrict__ g,
            const float* __restrict__ h, int n4) {
  int i = blockIdx.x * blockDim.x + threadIdx.x;
  int stride = gridDim.x * blockDim.x;
  for (; i < n4; i += stride) {
    float4 gv = ((const float4*)g)[i];
    float4 hv = ((const float4*)h)[i];
    float4 p;
    p.x = gv.x + hv.x; p.y = gv.y + hv.y; p.z = gv.z + hv.z; p.w = gv.w + hv.w;
    ((float4*)prev)[i] = p;
  }
}

// OUT = e0 + prev1 + g1 + h1   where prev1 = t0+h0
__global__ __launch_bounds__(256)
void final_k(float* __restrict__ oe, const float* __restrict__ u,
             const float* __restrict__ ie, const float* __restrict__ prev,
             const float* __restrict__ g1, const float* __restrict__ h1,
             int n4u, int n4) {
  int i = blockIdx.x * blockDim.x + threadIdx.x;
  int stride = gridDim.x * blockDim.x;
  for (; i < n4; i += stride) {
    float4 e0 = (i < n4u) ? ((const float4*)u)[i] : ((const float4*)ie)[i - n4u];
    float4 p = ((const float4*)prev)[i];
    float4 gv = ((const float4*)g1)[i];
    float4 hv = ((const float4*)h1)[i];
    float4 o;
    o.x = e0.x + p.x + gv.x + hv.x;
    o.y = e0.y + p.y + gv.y + hv.y;
    o.z = e0.z + p.z + gv.z + hv.z;
    o.w = e0.w + p.w + gv.w + hv.w;
    ((float4*)oe)[i] = o;
  }
}

extern "C" void kernel_launch(void* const* d_in, const int* in_sizes, int n_in,
                              void* d_out, int out_size, void* d_ws, size_t ws_size,
                              hipStream_t stream) {
  const float* u_emb = (const float*)d_in[0];
  const float* i_emb = (const float*)d_in[1];
  const float* u_hyp = (const float*)d_in[2];
  const float* i_hyp = (const float*)d_in[3];
  const float* Vm    = (const float*)d_in[4];
  const int*   rows  = (const int*)d_in[5];
  const int*   cols  = (const int*)d_in[6];
  const float* vals  = (const float*)d_in[7];
  int E = in_sizes[5];

  float* out = (float*)d_out;
  float* OUT_G = out + (size_t)NT * DD;        // gnn_lats [2,N,D]
  float* OUT_H = out + (size_t)3 * NT * DD;    // hyper_lats [2,N,D]

  float* ws = (float*)d_ws;
  float* prev  = ws;                            // NT*DD
  float* uuH   = prev + (size_t)NT * DD;        // NU*128
  float* iiH   = uuH + (size_t)NU * 128;        // NI*128
  float* lat_a = iiH + (size_t)NI * 128;        // 16384
  float* lat_b = lat_a + 16384;                 // 16384

  // prev = embeds0 = concat(u, i)
  hipMemcpyAsync(prev, u_emb, sizeof(float) * (size_t)NU * DD,
                 hipMemcpyDeviceToDevice, stream);
  hipMemcpyAsync(prev + (size_t)NU * DD, i_emb, sizeof(float) * (size_t)NI * DD,
                 hipMemcpyDeviceToDevice, stream);

  // uuHyper / iiHyper
  gemm_n128<false><<<(NU + 127) / 128, 256, 0, stream>>>(u_emb, u_hyp, uuH, NU);
  gemm_n128<false><<<(NI + 127) / 128, 256, 0, stream>>>(i_emb, i_hyp, iiH, NI);

  for (int k = 0; k < 2; ++k) {
    float* G = OUT_G + (size_t)k * NT * DD;
    float* H = OUT_H + (size_t)k * NT * DD;

    // tem = leaky(spmm(prev))
    hipMemsetAsync(G, 0, sizeof(float) * (size_t)NT * DD, stream);
    spmm_k<<<(E + 1) / 2, 256, 0, stream>>>(rows, cols, vals, prev, G, E);
    leaky_k<<<2048, 256, 0, stream>>>(G, NT * DD / 4);

    // hgnn users
    hipMemsetAsync(lat_a, 0, sizeof(float) * 16384, stream);
    gemm_tn_atomic<<<(NU + 255) / 256, 256, 0, stream>>>(uuH, prev, lat_a, NU, 256);
    leaky_k<<<16, 256, 0, stream>>>(lat_a, 16384 / 4);
    vgemm_res<<<16, 256, 0, stream>>>(Vm, lat_a, lat_b);
    vgemm_res<<<16, 256, 0, stream>>>(Vm, lat_b, lat_a);
    gemm_n128<true><<<(NU + 127) / 128, 256, 0, stream>>>(uuH, lat_a, H, NU);

    // hgnn items
    hipMemsetAsync(lat_a, 0, sizeof(float) * 16384, stream);
    gemm_tn_atomic<<<(NI + 255) / 256, 256, 0, stream>>>(
        iiH, prev + (size_t)NU * DD, lat_a, NI, 256);
    leaky_k<<<16, 256, 0, stream>>>(lat_a, 16384 / 4);
    vgemm_res<<<16, 256, 0, stream>>>(Vm, lat_a, lat_b);
    vgemm_res<<<16, 256, 0, stream>>>(Vm, lat_b, lat_a);
    gemm_n128<true><<<(NI + 127) / 128, 256, 0, stream>>>(
        iiH, lat_a, H + (size_t)NU * DD, NI);

    // layer output: prev = tem + hyp  (NO residual of previous prev)
    if (k == 0)
      set2_k<<<2048, 256, 0, stream>>>(prev, G, H, NT * DD / 4);
  }

  // embeds = e0 + (t0+h0) + (t1+h1)
  final_k<<<2048, 256, 0, stream>>>(out, u_emb, i_emb, prev,
                                    OUT_G + (size_t)NT * DD,
                                    OUT_H + (size_t)NT * DD,
                                    NU * DD / 4, NT * DD / 4);
}

// Round 3
// 1078.116 us; speedup vs baseline: 1.5204x; 1.5204x over previous
//
#include <hip/hip_runtime.h>

#define NU 50000
#define NI 70000
#define NT 120000
#define DD 128
#define EDG 800000
#define NCH ((NT + 255) / 256)   // 469 scan chunks
#define SLOPE 0.5f

typedef __attribute__((ext_vector_type(8))) short bf16x8;
typedef __attribute__((ext_vector_type(4))) float f32x4;

__device__ __forceinline__ float lrelu(float x) { return x >= 0.f ? x : SLOPE * x; }

__device__ __forceinline__ unsigned short f2bf(float x) {
  union { float f; unsigned u; } t; t.f = x;
  unsigned r = (t.u + 0x7fffu + ((t.u >> 16) & 1u)) >> 16;
  return (unsigned short)r;
}

// ---------------- edge sort (counting sort by row) ----------------

__global__ __launch_bounds__(256)
void hist_k(const int* __restrict__ rows, int* __restrict__ cnt, int E) {
  int e = blockIdx.x * 256 + threadIdx.x;
  if (e < E) atomicAdd(&cnt[rows[e]], 1);
}

__global__ __launch_bounds__(256)
void scan1_k(const int* __restrict__ cnt, int* __restrict__ tmp, int* __restrict__ part) {
  __shared__ int s[256];
  int gid = blockIdx.x * 256 + threadIdx.x;
  s[threadIdx.x] = (gid < NT) ? cnt[gid] : 0;
  __syncthreads();
#pragma unroll
  for (int off = 1; off < 256; off <<= 1) {
    int add = (threadIdx.x >= off) ? s[threadIdx.x - off] : 0;
    __syncthreads();
    s[threadIdx.x] += add;
    __syncthreads();
  }
  if (gid < NT) tmp[gid] = s[threadIdx.x];
  if (threadIdx.x == 255) part[blockIdx.x] = s[255];
}

__global__ __launch_bounds__(512)
void scan2_k(int* __restrict__ part) {
  __shared__ int s[512];
  s[threadIdx.x] = (threadIdx.x < NCH) ? part[threadIdx.x] : 0;
  __syncthreads();
#pragma unroll
  for (int off = 1; off < 512; off <<= 1) {
    int add = (threadIdx.x >= off) ? s[threadIdx.x - off] : 0;
    __syncthreads();
    s[threadIdx.x] += add;
    __syncthreads();
  }
  if (threadIdx.x < NCH) part[threadIdx.x] = s[threadIdx.x];
}

__global__ __launch_bounds__(256)
void scan3_k(const int* __restrict__ tmp, const int* __restrict__ part,
             int* __restrict__ row_ptr) {
  int gid = blockIdx.x * 256 + threadIdx.x;
  if (gid < NT) {
    int off = blockIdx.x ? part[blockIdx.x - 1] : 0;
    row_ptr[gid + 1] = tmp[gid] + off;
  }
  if (gid == 0) row_ptr[0] = 0;
}

__global__ __launch_bounds__(256)
void scatter_k(const int* __restrict__ rows, const int* __restrict__ cols,
               const float* __restrict__ vals, const int* __restrict__ row_ptr,
               int* __restrict__ cursor, int* __restrict__ scol,
               float* __restrict__ sval, int E) {
  int e = blockIdx.x * 256 + threadIdx.x;
  if (e >= E) return;
  int r = rows[e];
  int p = row_ptr[r] + atomicAdd(&cursor[r], 1);
  scol[p] = cols[e];
  sval[p] = vals[e];
}

// out[r,:] = lrelu(sum_e val * prev[col,:]) ; one wave per row, 2 dims/lane.
__global__ __launch_bounds__(256)
void spmm_row_k(const int* __restrict__ row_ptr, const int* __restrict__ scol,
                const float* __restrict__ sval, const float* __restrict__ prev,
                float* __restrict__ out) {
  int wv = threadIdx.x >> 6, lane = threadIdx.x & 63;
  int r = blockIdx.x * 4 + wv;
  int p0 = row_ptr[r], p1 = row_ptr[r + 1];
  float ax = 0.f, ay = 0.f;
  for (int p = p0; p < p1; ++p) {
    int c = scol[p];
    float v = sval[p];
    float2 x = *(const float2*)(prev + (size_t)c * DD + lane * 2);
    ax = fmaf(v, x.x, ax);
    ay = fmaf(v, x.y, ay);
  }
  float2 o; o.x = lrelu(ax); o.y = lrelu(ay);
  *(float2*)(out + (size_t)r * DD + lane * 2) = o;
}

// ---------------- dense GEMMs ----------------

// BT[c*128+k] = bf16(B[k*128+c])
__global__ __launch_bounds__(256)
void transp_cvt(const float* __restrict__ B, unsigned short* __restrict__ BT) {
  for (int i = threadIdx.x; i < 16384; i += 256) {
    int r = i >> 7, c = i & 127;
    BT[c * 128 + r] = f2bf(B[r * 128 + c]);
  }
}

// C[n,128] = act(A[n,128] @ B) with BT = bf16 B^T[col][k]. 64 rows/block, 4 waves.
template<bool LEAKY>
__global__ __launch_bounds__(256)
void gemm_mfma(const float* __restrict__ A, const unsigned short* __restrict__ BT,
               float* __restrict__ C, int n) {
  int wv = threadIdx.x >> 6, lane = threadIdx.x & 63;
  int t = lane & 15, g = lane >> 4;
  int rowa = blockIdx.x * 64 + wv * 16 + t;
  int ra = rowa < n ? rowa : (n - 1);
  const float* ap = A + (size_t)ra * DD;

  bf16x8 af[4];
#pragma unroll
  for (int k0 = 0; k0 < 4; ++k0) {
    float4 x = *(const float4*)(ap + k0 * 32 + g * 8);
    float4 y = *(const float4*)(ap + k0 * 32 + g * 8 + 4);
    bf16x8 v;
    v[0] = (short)f2bf(x.x); v[1] = (short)f2bf(x.y);
    v[2] = (short)f2bf(x.z); v[3] = (short)f2bf(x.w);
    v[4] = (short)f2bf(y.x); v[5] = (short)f2bf(y.y);
    v[6] = (short)f2bf(y.z); v[7] = (short)f2bf(y.w);
    af[k0] = v;
  }

  f32x4 acc[8];
#pragma unroll
  for (int cb = 0; cb < 8; ++cb) acc[cb] = (f32x4){0.f, 0.f, 0.f, 0.f};

#pragma unroll
  for (int k0 = 0; k0 < 4; ++k0) {
#pragma unroll
    for (int cb = 0; cb < 8; ++cb) {
      bf16x8 bfr = *(const bf16x8*)(BT + (size_t)(cb * 16 + t) * 128 + k0 * 32 + g * 8);
      acc[cb] = __builtin_amdgcn_mfma_f32_16x16x32_bf16(af[k0], bfr, acc[cb], 0, 0, 0);
    }
  }

  int rbase = blockIdx.x * 64 + wv * 16 + g * 4;
#pragma unroll
  for (int cb = 0; cb < 8; ++cb) {
#pragma unroll
    for (int r = 0; r < 4; ++r) {
      int orow = rbase + r;
      if (orow < n) {
        float v = acc[cb][r];
        if (LEAKY) v = lrelu(v);
        C[(size_t)orow * DD + cb * 16 + t] = v;
      }
    }
  }
}

// out[128,128] += A[n,128]^T @ B[n,128] over this block's row chunk (atomic).
__global__ __launch_bounds__(256)
void gemm_tn_atomic(const float* __restrict__ A, const float* __restrict__ B,
                    float* __restrict__ out, int n, int chunk) {
  __shared__ float As[8][128];
  __shared__ float Bs[8][128];
  int tid = threadIdx.x;
  int ty = tid >> 4, tx = tid & 15;
  float acc[8][8];
#pragma unroll
  for (int i = 0; i < 8; ++i)
#pragma unroll
    for (int j = 0; j < 8; ++j) acc[i][j] = 0.f;

  int r0 = blockIdx.x * chunk;
  int r1 = min(r0 + chunk, n);
  int rr = tid >> 5;
  int cc = (tid & 31) * 4;

  for (int rb = r0; rb < r1; rb += 8) {
    int gr = rb + rr;
    float4 av = make_float4(0.f, 0.f, 0.f, 0.f);
    float4 bv = make_float4(0.f, 0.f, 0.f, 0.f);
    if (gr < r1) {
      av = *(const float4*)(A + (size_t)gr * DD + cc);
      bv = *(const float4*)(B + (size_t)gr * DD + cc);
    }
    __syncthreads();
    *(float4*)&As[rr][cc] = av;
    *(float4*)&Bs[rr][cc] = bv;
    __syncthreads();
#pragma unroll
    for (int r2 = 0; r2 < 8; ++r2) {
      float a[8], b[8];
      *(float4*)&a[0] = *(const float4*)&As[r2][ty * 8];
      *(float4*)&a[4] = *(const float4*)&As[r2][ty * 8 + 4];
      *(float4*)&b[0] = *(const float4*)&Bs[r2][tx * 4];
      *(float4*)&b[4] = *(const float4*)&Bs[r2][tx * 4 + 64];
#pragma unroll
      for (int i = 0; i < 8; ++i)
#pragma unroll
        for (int j = 0; j < 8; ++j)
          acc[i][j] = fmaf(a[i], b[j], acc[i][j]);
    }
  }

#pragma unroll
  for (int i = 0; i < 8; ++i) {
    int h = ty * 8 + i;
#pragma unroll
    for (int j = 0; j < 8; ++j) {
      int d = tx * 4 + (j < 4 ? j : 64 + (j - 4));
      atomicAdd(out + h * DD + d, acc[i][j]);
    }
  }
}

// out = leaky(V @ lat) + lat
__global__ __launch_bounds__(256)
void vgemm_res(const float* __restrict__ V, const float* __restrict__ lat,
               float* __restrict__ out) {
  int row = blockIdx.x * 8 + (threadIdx.x >> 5);
  int c4 = (threadIdx.x & 31) * 4;
  float4 acc = make_float4(0.f, 0.f, 0.f, 0.f);
  for (int k = 0; k < 128; ++k) {
    float v = V[row * 128 + k];
    float4 l = *(const float4*)(lat + k * 128 + c4);
    acc.x = fmaf(v, l.x, acc.x);
    acc.y = fmaf(v, l.y, acc.y);
    acc.z = fmaf(v, l.z, acc.z);
    acc.w = fmaf(v, l.w, acc.w);
  }
  float4 r = *(const float4*)(lat + row * 128 + c4);
  float4 o;
  o.x = lrelu(acc.x) + r.x;
  o.y = lrelu(acc.y) + r.y;
  o.z = lrelu(acc.z) + r.z;
  o.w = lrelu(acc.w) + r.w;
  *(float4*)(out + row * 128 + c4) = o;
}

// same but writes bf16 transposed: BT[c][row]
__global__ __launch_bounds__(256)
void vgemm_res_t(const float* __restrict__ V, const float* __restrict__ lat,
                 unsigned short* __restrict__ BT) {
  int row = blockIdx.x * 8 + (threadIdx.x >> 5);
  int c4 = (threadIdx.x & 31) * 4;
  float4 acc = make_float4(0.f, 0.f, 0.f, 0.f);
  for (int k = 0; k < 128; ++k) {
    float v = V[row * 128 + k];
    float4 l = *(const float4*)(lat + k * 128 + c4);
    acc.x = fmaf(v, l.x, acc.x);
    acc.y = fmaf(v, l.y, acc.y);
    acc.z = fmaf(v, l.z, acc.z);
    acc.w = fmaf(v, l.w, acc.w);
  }
  float4 r = *(const float4*)(lat + row * 128 + c4);
  BT[(size_t)(c4 + 0) * 128 + row] = f2bf(lrelu(acc.x) + r.x);
  BT[(size_t)(c4 + 1) * 128 + row] = f2bf(lrelu(acc.y) + r.y);
  BT[(size_t)(c4 + 2) * 128 + row] = f2bf(lrelu(acc.z) + r.z);
  BT[(size_t)(c4 + 3) * 128 + row] = f2bf(lrelu(acc.w) + r.w);
}

__global__ __launch_bounds__(256)
void leaky_k(float* __restrict__ p, int n4) {
  int i = blockIdx.x * blockDim.x + threadIdx.x;
  int stride = gridDim.x * blockDim.x;
  for (; i < n4; i += stride) {
    float4 v = ((float4*)p)[i];
    v.x = lrelu(v.x); v.y = lrelu(v.y); v.z = lrelu(v.z); v.w = lrelu(v.w);
    ((float4*)p)[i] = v;
  }
}

// prev = g + h
__global__ __launch_bounds__(256)
void set2_k(float* __restrict__ prev, const float* __restrict__ g,
            const float* __restrict__ h, int n4) {
  int i = blockIdx.x * blockDim.x + threadIdx.x;
  int stride = gridDim.x * blockDim.x;
  for (; i < n4; i += stride) {
    float4 gv = ((const float4*)g)[i];
    float4 hv = ((const float4*)h)[i];
    float4 p;
    p.x = gv.x + hv.x; p.y = gv.y + hv.y; p.z = gv.z + hv.z; p.w = gv.w + hv.w;
    ((float4*)prev)[i] = p;
  }
}

// OUT = e0 + prev1 + g1 + h1
__global__ __launch_bounds__(256)
void final_k(float* __restrict__ oe, const float* __restrict__ u,
             const float* __restrict__ ie, const float* __restrict__ prev,
             const float* __restrict__ g1, const float* __restrict__ h1,
             int n4u, int n4) {
  int i = blockIdx.x * blockDim.x + threadIdx.x;
  int stride = gridDim.x * blockDim.x;
  for (; i < n4; i += stride) {
    float4 e0 = (i < n4u) ? ((const float4*)u)[i] : ((const float4*)ie)[i - n4u];
    float4 p = ((const float4*)prev)[i];
    float4 gv = ((const float4*)g1)[i];
    float4 hv = ((const float4*)h1)[i];
    float4 o;
    o.x = e0.x + p.x + gv.x + hv.x;
    o.y = e0.y + p.y + gv.y + hv.y;
    o.z = e0.z + p.z + gv.z + hv.z;
    o.w = e0.w + p.w + gv.w + hv.w;
    ((float4*)oe)[i] = o;
  }
}

extern "C" void kernel_launch(void* const* d_in, const int* in_sizes, int n_in,
                              void* d_out, int out_size, void* d_ws, size_t ws_size,
                              hipStream_t stream) {
  const float* u_emb = (const float*)d_in[0];
  const float* i_emb = (const float*)d_in[1];
  const float* u_hyp = (const float*)d_in[2];
  const float* i_hyp = (const float*)d_in[3];
  const float* Vm    = (const float*)d_in[4];
  const int*   rows  = (const int*)d_in[5];
  const int*   cols  = (const int*)d_in[6];
  const float* vals  = (const float*)d_in[7];
  int E = in_sizes[5];

  float* out = (float*)d_out;
  float* OUT_G = out + (size_t)NT * DD;        // gnn_lats [2,N,D]
  float* OUT_H = out + (size_t)3 * NT * DD;    // hyper_lats [2,N,D]

  char* w = (char*)d_ws;
  float* prev = (float*)w;            w += (size_t)NT * DD * 4;
  float* uuH  = (float*)w;            w += (size_t)NU * DD * 4;
  float* iiH  = (float*)w;            w += (size_t)NI * DD * 4;
  float* lat_a = (float*)w;           w += 16384 * 4;
  float* lat_b = (float*)w;           w += 16384 * 4;
  unsigned short* uhT = (unsigned short*)w;  w += 16384 * 2;
  unsigned short* ihT = (unsigned short*)w;  w += 16384 * 2;
  unsigned short* latT = (unsigned short*)w; w += 16384 * 2;
  int* row_cnt = (int*)w;             w += (size_t)NT * 4;
  int* row_ptr = (int*)w;             w += (size_t)(NT + 1) * 4;
  int* tmp     = (int*)w;             w += (size_t)NT * 4;
  int* part    = (int*)w;             w += 512 * 4;
  int* cursor  = (int*)w;             w += (size_t)NT * 4;
  int* scol    = (int*)w;             w += (size_t)EDG * 4;
  float* sval  = (float*)w;           w += (size_t)EDG * 4;

  // prev = embeds0
  hipMemcpyAsync(prev, u_emb, sizeof(float) * (size_t)NU * DD,
                 hipMemcpyDeviceToDevice, stream);
  hipMemcpyAsync(prev + (size_t)NU * DD, i_emb, sizeof(float) * (size_t)NI * DD,
                 hipMemcpyDeviceToDevice, stream);

  // ---- sort edges by row (once; reused by both layers) ----
  hipMemsetAsync(row_cnt, 0, sizeof(int) * NT, stream);
  hipMemsetAsync(cursor, 0, sizeof(int) * NT, stream);
  hist_k<<<(E + 255) / 256, 256, 0, stream>>>(rows, row_cnt, E);
  scan1_k<<<NCH, 256, 0, stream>>>(row_cnt, tmp, part);
  scan2_k<<<1, 512, 0, stream>>>(part);
  scan3_k<<<NCH, 256, 0, stream>>>(tmp, part, row_ptr);
  scatter_k<<<(E + 255) / 256, 256, 0, stream>>>(rows, cols, vals, row_ptr,
                                                 cursor, scol, sval, E);

  // ---- hyper projections ----
  transp_cvt<<<1, 256, 0, stream>>>(u_hyp, uhT);
  transp_cvt<<<1, 256, 0, stream>>>(i_hyp, ihT);
  gemm_mfma<false><<<(NU + 63) / 64, 256, 0, stream>>>(u_emb, uhT, uuH, NU);
  gemm_mfma<false><<<(NI + 63) / 64, 256, 0, stream>>>(i_emb, ihT, iiH, NI);

  for (int k = 0; k < 2; ++k) {
    float* G = OUT_G + (size_t)k * NT * DD;
    float* H = OUT_H + (size_t)k * NT * DD;

    // tem = leaky(spmm(prev))  — sorted segmented sum, fused leaky
    spmm_row_k<<<NT / 4, 256, 0, stream>>>(row_ptr, scol, sval, prev, G);

    // hgnn users
    hipMemsetAsync(lat_a, 0, sizeof(float) * 16384, stream);
    gemm_tn_atomic<<<(NU + 255) / 256, 256, 0, stream>>>(uuH, prev, lat_a, NU, 256);
    leaky_k<<<16, 256, 0, stream>>>(lat_a, 16384 / 4);
    vgemm_res<<<16, 256, 0, stream>>>(Vm, lat_a, lat_b);
    vgemm_res_t<<<16, 256, 0, stream>>>(Vm, lat_b, latT);
    gemm_mfma<true><<<(NU + 63) / 64, 256, 0, stream>>>(uuH, latT, H, NU);

    // hgnn items
    hipMemsetAsync(lat_a, 0, sizeof(float) * 16384, stream);
    gemm_tn_atomic<<<(NI + 255) / 256, 256, 0, stream>>>(
        iiH, prev + (size_t)NU * DD, lat_a, NI, 256);
    leaky_k<<<16, 256, 0, stream>>>(lat_a, 16384 / 4);
    vgemm_res<<<16, 256, 0, stream>>>(Vm, lat_a, lat_b);
    vgemm_res_t<<<16, 256, 0, stream>>>(Vm, lat_b, latT);
    gemm_mfma<true><<<(NI + 63) / 64, 256, 0, stream>>>(
        iiH, latT, H + (size_t)NU * DD, NI);

    // prev = tem + hyp
    if (k == 0)
      set2_k<<<2048, 256, 0, stream>>>(prev, G, H, NT * DD / 4);
  }

  // embeds = e0 + (t0+h0) + (t1+h1)
  final_k<<<2048, 256, 0, stream>>>(out, u_emb, i_emb, prev,
                                    OUT_G + (size_t)NT * DD,
                                    OUT_H + (size_t)NT * DD,
                                    NU * DD / 4, NT * DD / 4);
}

// Round 4
// 911.884 us; speedup vs baseline: 1.7976x; 1.1823x over previous
//
#include <hip/hip_runtime.h>

#define NU 50000
#define NI 70000
#define NT 120000
#define DD 128
#define EDG 800000
#define NCH ((NT + 255) / 256)      // 469 scan chunks
#define NBU_TN ((NU + 255) / 256)   // 196
#define NBI_TN ((NI + 255) / 256)   // 274
#define NBU_M ((NU + 63) / 64)      // 782
#define NBI_M ((NI + 63) / 64)      // 1094
#define SLOPE 0.5f

typedef __attribute__((ext_vector_type(8))) short bf16x8;
typedef __attribute__((ext_vector_type(4))) float f32x4;

__device__ __forceinline__ float lrelu(float x) { return x >= 0.f ? x : SLOPE * x; }

__device__ __forceinline__ unsigned short f2bf(float x) {
  union { float f; unsigned u; } t; t.f = x;
  unsigned r = (t.u + 0x7fffu + ((t.u >> 16) & 1u)) >> 16;
  return (unsigned short)r;
}

// ---------------- edge sort (counting sort by row) ----------------

__global__ __launch_bounds__(256)
void hist_k(const int* __restrict__ rows, int* __restrict__ cnt, int E) {
  int e = blockIdx.x * 256 + threadIdx.x;
  if (e < E) atomicAdd(&cnt[rows[e]], 1);
}

__global__ __launch_bounds__(256)
void scan1_k(const int* __restrict__ cnt, int* __restrict__ tmp, int* __restrict__ part) {
  __shared__ int s[256];
  int gid = blockIdx.x * 256 + threadIdx.x;
  s[threadIdx.x] = (gid < NT) ? cnt[gid] : 0;
  __syncthreads();
#pragma unroll
  for (int off = 1; off < 256; off <<= 1) {
    int add = (threadIdx.x >= off) ? s[threadIdx.x - off] : 0;
    __syncthreads();
    s[threadIdx.x] += add;
    __syncthreads();
  }
  if (gid < NT) tmp[gid] = s[threadIdx.x];
  if (threadIdx.x == 255) part[blockIdx.x] = s[255];
}

__global__ __launch_bounds__(512)
void scan2_k(int* __restrict__ part) {
  __shared__ int s[512];
  s[threadIdx.x] = (threadIdx.x < NCH) ? part[threadIdx.x] : 0;
  __syncthreads();
#pragma unroll
  for (int off = 1; off < 512; off <<= 1) {
    int add = (threadIdx.x >= off) ? s[threadIdx.x - off] : 0;
    __syncthreads();
    s[threadIdx.x] += add;
    __syncthreads();
  }
  if (threadIdx.x < NCH) part[threadIdx.x] = s[threadIdx.x];
}

__global__ __launch_bounds__(256)
void scan3_k(const int* __restrict__ tmp, const int* __restrict__ part,
             int* __restrict__ row_ptr) {
  int gid = blockIdx.x * 256 + threadIdx.x;
  if (gid < NT) {
    int off = blockIdx.x ? part[blockIdx.x - 1] : 0;
    row_ptr[gid + 1] = tmp[gid] + off;
  }
  if (gid == 0) row_ptr[0] = 0;
}

__global__ __launch_bounds__(256)
void scatter_k(const int* __restrict__ rows, const int* __restrict__ cols,
               const float* __restrict__ vals, const int* __restrict__ row_ptr,
               int* __restrict__ cursor, int2* __restrict__ sedge, int E) {
  int e = blockIdx.x * 256 + threadIdx.x;
  if (e >= E) return;
  int r = rows[e];
  int p = row_ptr[r] + atomicAdd(&cursor[r], 1);
  int2 ev; ev.x = cols[e]; ev.y = __float_as_int(vals[e]);
  sedge[p] = ev;
}

// out[r,:] = lrelu(sum_e val * src[col,:]) ; one wave per row, 2 dims/lane.
__global__ __launch_bounds__(256)
void spmm_row_k(const int* __restrict__ rp, const int2* __restrict__ se,
                const float* __restrict__ pu, const float* __restrict__ pi,
                float* __restrict__ out) {
  int wv = threadIdx.x >> 6, lane = threadIdx.x & 63;
  int r = blockIdx.x * 4 + wv;
  int p0 = rp[r], p1 = rp[r + 1];
  float ax = 0.f, ay = 0.f;
  for (int p = p0; p < p1; ++p) {
    int2 e = se[p];
    float v = __int_as_float(e.y);
    const float* src = (e.x < NU) ? pu + (size_t)e.x * DD
                                  : pi + (size_t)(e.x - NU) * DD;
    float2 x = *(const float2*)(src + lane * 2);
    ax = fmaf(v, x.x, ax);
    ay = fmaf(v, x.y, ay);
  }
  float2 o; o.x = lrelu(ax); o.y = lrelu(ay);
  *(float2*)(out + (size_t)r * DD + lane * 2) = o;
}

// ---------------- dense kernels ----------------

// block 0: uhT = bf16(u_hyp^T); block 1: ihT = bf16(i_hyp^T)
__global__ __launch_bounds__(256)
void transp_both(const float* __restrict__ uh, const float* __restrict__ ih,
                 unsigned short* __restrict__ uhT, unsigned short* __restrict__ ihT) {
  const float* B = blockIdx.x ? ih : uh;
  unsigned short* BT = blockIdx.x ? ihT : uhT;
  for (int i = threadIdx.x; i < 16384; i += 256) {
    int r = i >> 7, c = i & 127;
    BT[c * 128 + r] = f2bf(B[r * 128 + c]);
  }
}

// projections: uuH = u_emb @ u_hyp ; iiH = i_emb @ i_hyp. 64 rows/block, merged.
__global__ __launch_bounds__(256)
void proj_mfma(const float* __restrict__ Au, const float* __restrict__ Ai,
               const unsigned short* __restrict__ BTu, const unsigned short* __restrict__ BTi,
               float* __restrict__ Cu, float* __restrict__ Ci) {
  int b = blockIdx.x;
  bool usr = b < NBU_M;
  const float* A = usr ? Au : Ai;
  const unsigned short* BT = usr ? BTu : BTi;
  float* C = usr ? Cu : Ci;
  int n = usr ? NU : NI;
  int lb = usr ? b : b - NBU_M;

  int wv = threadIdx.x >> 6, lane = threadIdx.x & 63;
  int t = lane & 15, g = lane >> 4;
  int rowa = lb * 64 + wv * 16 + t;
  int ra = rowa < n ? rowa : (n - 1);
  const float* ap = A + (size_t)ra * DD;

  bf16x8 af[4];
#pragma unroll
  for (int k0 = 0; k0 < 4; ++k0) {
    float4 x = *(const float4*)(ap + k0 * 32 + g * 8);
    float4 y = *(const float4*)(ap + k0 * 32 + g * 8 + 4);
    bf16x8 v;
    v[0] = (short)f2bf(x.x); v[1] = (short)f2bf(x.y);
    v[2] = (short)f2bf(x.z); v[3] = (short)f2bf(x.w);
    v[4] = (short)f2bf(y.x); v[5] = (short)f2bf(y.y);
    v[6] = (short)f2bf(y.z); v[7] = (short)f2bf(y.w);
    af[k0] = v;
  }

  f32x4 acc[8];
#pragma unroll
  for (int cb = 0; cb < 8; ++cb) acc[cb] = (f32x4){0.f, 0.f, 0.f, 0.f};
#pragma unroll
  for (int k0 = 0; k0 < 4; ++k0)
#pragma unroll
    for (int cb = 0; cb < 8; ++cb) {
      bf16x8 bfr = *(const bf16x8*)(BT + (size_t)(cb * 16 + t) * 128 + k0 * 32 + g * 8);
      acc[cb] = __builtin_amdgcn_mfma_f32_16x16x32_bf16(af[k0], bfr, acc[cb], 0, 0, 0);
    }

  int rbase = lb * 64 + wv * 16 + g * 4;
#pragma unroll
  for (int cb = 0; cb < 8; ++cb)
#pragma unroll
    for (int j = 0; j < 4; ++j) {
      int lr = rbase + j;
      if (lr < n) C[(size_t)lr * DD + cb * 16 + t] = acc[cb][j];
    }
}

// hyper GEMM + fused epilogue. LAYER 0: H=lrelu(acc), prev=G+H.
// LAYER 1: H=lrelu(acc), out=e0+prev+G+H.
template<int LAYER>
__global__ __launch_bounds__(256)
void hyp_mfma(const float* __restrict__ Au, const float* __restrict__ Ai,
              const unsigned short* __restrict__ BTu, const unsigned short* __restrict__ BTi,
              const float* __restrict__ G, float* __restrict__ prev,
              const float* __restrict__ ue, const float* __restrict__ ie,
              float* __restrict__ H, float* __restrict__ out) {
  int b = blockIdx.x;
  bool usr = b < NBU_M;
  const float* A = usr ? Au : Ai;
  const unsigned short* BT = usr ? BTu : BTi;
  int n = usr ? NU : NI;
  int lb = usr ? b : b - NBU_M;
  int gbase = usr ? 0 : NU;

  int wv = threadIdx.x >> 6, lane = threadIdx.x & 63;
  int t = lane & 15, g = lane >> 4;
  int rowa = lb * 64 + wv * 16 + t;
  int ra = rowa < n ? rowa : (n - 1);
  const float* ap = A + (size_t)ra * DD;

  bf16x8 af[4];
#pragma unroll
  for (int k0 = 0; k0 < 4; ++k0) {
    float4 x = *(const float4*)(ap + k0 * 32 + g * 8);
    float4 y = *(const float4*)(ap + k0 * 32 + g * 8 + 4);
    bf16x8 v;
    v[0] = (short)f2bf(x.x); v[1] = (short)f2bf(x.y);
    v[2] = (short)f2bf(x.z); v[3] = (short)f2bf(x.w);
    v[4] = (short)f2bf(y.x); v[5] = (short)f2bf(y.y);
    v[6] = (short)f2bf(y.z); v[7] = (short)f2bf(y.w);
    af[k0] = v;
  }

  f32x4 acc[8];
#pragma unroll
  for (int cb = 0; cb < 8; ++cb) acc[cb] = (f32x4){0.f, 0.f, 0.f, 0.f};
#pragma unroll
  for (int k0 = 0; k0 < 4; ++k0)
#pragma unroll
    for (int cb = 0; cb < 8; ++cb) {
      bf16x8 bfr = *(const bf16x8*)(BT + (size_t)(cb * 16 + t) * 128 + k0 * 32 + g * 8);
      acc[cb] = __builtin_amdgcn_mfma_f32_16x16x32_bf16(af[k0], bfr, acc[cb], 0, 0, 0);
    }

  int rbase = lb * 64 + wv * 16 + g * 4;
#pragma unroll
  for (int cb = 0; cb < 8; ++cb)
#pragma unroll
    for (int j = 0; j < 4; ++j) {
      int lr = rbase + j;
      if (lr < n) {
        size_t gi = (size_t)(gbase + lr) * DD + cb * 16 + t;
        float h = lrelu(acc[cb][j]);
        H[gi] = h;
        if (LAYER == 0) {
          prev[gi] = G[gi] + h;
        } else {
          float e0 = usr ? ue[(size_t)lr * DD + cb * 16 + t]
                         : ie[(size_t)lr * DD + cb * 16 + t];
          out[gi] = e0 + prev[gi] + G[gi] + h;
        }
      }
    }
}

// lat reductions: latU += uuH^T @ Bu ; latI += iiH^T @ Bi (atomic, merged u/i).
__global__ __launch_bounds__(256)
void tn_both(const float* __restrict__ Au, const float* __restrict__ Ai,
             const float* __restrict__ Bu, const float* __restrict__ Bi,
             float* __restrict__ latU, float* __restrict__ latI) {
  int b = blockIdx.x;
  bool usr = b < NBU_TN;
  const float* A = usr ? Au : Ai;
  const float* B = usr ? Bu : Bi;
  float* outp = usr ? latU : latI;
  int n = usr ? NU : NI;
  int r0 = (usr ? b : b - NBU_TN) * 256;
  int r1 = min(r0 + 256, n);

  __shared__ float As[8][128];
  __shared__ float Bs[8][128];
  int tid = threadIdx.x;
  int ty = tid >> 4, tx = tid & 15;
  float acc[8][8];
#pragma unroll
  for (int i = 0; i < 8; ++i)
#pragma unroll
    for (int j = 0; j < 8; ++j) acc[i][j] = 0.f;

  int rr = tid >> 5;
  int cc = (tid & 31) * 4;

  for (int rb = r0; rb < r1; rb += 8) {
    int gr = rb + rr;
    float4 av = make_float4(0.f, 0.f, 0.f, 0.f);
    float4 bv = make_float4(0.f, 0.f, 0.f, 0.f);
    if (gr < r1) {
      av = *(const float4*)(A + (size_t)gr * DD + cc);
      bv = *(const float4*)(B + (size_t)gr * DD + cc);
    }
    __syncthreads();
    *(float4*)&As[rr][cc] = av;
    *(float4*)&Bs[rr][cc] = bv;
    __syncthreads();
#pragma unroll
    for (int r2 = 0; r2 < 8; ++r2) {
      float a[8], bb[8];
      *(float4*)&a[0] = *(const float4*)&As[r2][ty * 8];
      *(float4*)&a[4] = *(const float4*)&As[r2][ty * 8 + 4];
      *(float4*)&bb[0] = *(const float4*)&Bs[r2][tx * 4];
      *(float4*)&bb[4] = *(const float4*)&Bs[r2][tx * 4 + 64];
#pragma unroll
      for (int i = 0; i < 8; ++i)
#pragma unroll
        for (int j = 0; j < 8; ++j)
          acc[i][j] = fmaf(a[i], bb[j], acc[i][j]);
    }
  }

#pragma unroll
  for (int i = 0; i < 8; ++i) {
    int h = ty * 8 + i;
#pragma unroll
    for (int j = 0; j < 8; ++j) {
      int d = tx * 4 + (j < 4 ? j : 64 + (j - 4));
      atomicAdd(outp + h * DD + d, acc[i][j]);
    }
  }
}

// pass 1: out = lrelu(V @ L) + L, where L = lrelu(in_raw). merged u/i, 32 blocks.
__global__ __launch_bounds__(256)
void vg1_k(const float* __restrict__ V, const float* __restrict__ inU,
           const float* __restrict__ inI, float* __restrict__ outU,
           float* __restrict__ outI) {
  const float* in = blockIdx.x < 16 ? inU : inI;
  float* outp = blockIdx.x < 16 ? outU : outI;
  int row = (blockIdx.x & 15) * 8 + (threadIdx.x >> 5);
  int c4 = (threadIdx.x & 31) * 4;
  float4 acc = make_float4(0.f, 0.f, 0.f, 0.f);
  for (int k = 0; k < 128; ++k) {
    float v = V[row * 128 + k];
    float4 l = *(const float4*)(in + k * 128 + c4);
    l.x = lrelu(l.x); l.y = lrelu(l.y); l.z = lrelu(l.z); l.w = lrelu(l.w);
    acc.x = fmaf(v, l.x, acc.x);
    acc.y = fmaf(v, l.y, acc.y);
    acc.z = fmaf(v, l.z, acc.z);
    acc.w = fmaf(v, l.w, acc.w);
  }
  float4 r = *(const float4*)(in + row * 128 + c4);
  float4 o;
  o.x = lrelu(acc.x) + lrelu(r.x);
  o.y = lrelu(acc.y) + lrelu(r.y);
  o.z = lrelu(acc.z) + lrelu(r.z);
  o.w = lrelu(acc.w) + lrelu(r.w);
  *(float4*)(outp + row * 128 + c4) = o;
}

// pass 2: BT = bf16( (lrelu(V @ L) + L)^T ), L proper. merged u/i.
__global__ __launch_bounds__(256)
void vg2_k(const float* __restrict__ V, const float* __restrict__ inU,
           const float* __restrict__ inI, unsigned short* __restrict__ outU,
           unsigned short* __restrict__ outI) {
  const float* in = blockIdx.x < 16 ? inU : inI;
  unsigned short* BT = blockIdx.x < 16 ? outU : outI;
  int row = (blockIdx.x & 15) * 8 + (threadIdx.x >> 5);
  int c4 = (threadIdx.x & 31) * 4;
  float4 acc = make_float4(0.f, 0.f, 0.f, 0.f);
  for (int k = 0; k < 128; ++k) {
    float v = V[row * 128 + k];
    float4 l = *(const float4*)(in + k * 128 + c4);
    acc.x = fmaf(v, l.x, acc.x);
    acc.y = fmaf(v, l.y, acc.y);
    acc.z = fmaf(v, l.z, acc.z);
    acc.w = fmaf(v, l.w, acc.w);
  }
  float4 r = *(const float4*)(in + row * 128 + c4);
  BT[(size_t)(c4 + 0) * 128 + row] = f2bf(lrelu(acc.x) + r.x);
  BT[(size_t)(c4 + 1) * 128 + row] = f2bf(lrelu(acc.y) + r.y);
  BT[(size_t)(c4 + 2) * 128 + row] = f2bf(lrelu(acc.z) + r.z);
  BT[(size_t)(c4 + 3) * 128 + row] = f2bf(lrelu(acc.w) + r.w);
}

extern "C" void kernel_launch(void* const* d_in, const int* in_sizes, int n_in,
                              void* d_out, int out_size, void* d_ws, size_t ws_size,
                              hipStream_t stream) {
  const float* u_emb = (const float*)d_in[0];
  const float* i_emb = (const float*)d_in[1];
  const float* u_hyp = (const float*)d_in[2];
  const float* i_hyp = (const float*)d_in[3];
  const float* Vm    = (const float*)d_in[4];
  const int*   rows  = (const int*)d_in[5];
  const int*   cols  = (const int*)d_in[6];
  const float* vals  = (const float*)d_in[7];
  int E = in_sizes[5];

  float* out = (float*)d_out;
  float* OUT_G = out + (size_t)NT * DD;        // gnn_lats [2,N,D]
  float* OUT_H = out + (size_t)3 * NT * DD;    // hyper_lats [2,N,D]

  char* w = (char*)d_ws;
  float* prev = (float*)w;            w += (size_t)NT * DD * 4;
  float* uuH  = (float*)w;            w += (size_t)NU * DD * 4;
  float* iiH  = (float*)w;            w += (size_t)NI * DD * 4;
  float* latU = (float*)w;            w += 16384 * 4;
  float* latI = (float*)w;            w += 16384 * 4;   // contiguous with latU
  float* lat2U = (float*)w;           w += 16384 * 4;
  float* lat2I = (float*)w;           w += 16384 * 4;
  unsigned short* uhT = (unsigned short*)w;   w += 16384 * 2;
  unsigned short* ihT = (unsigned short*)w;   w += 16384 * 2;
  unsigned short* latTu = (unsigned short*)w; w += 16384 * 2;
  unsigned short* latTi = (unsigned short*)w; w += 16384 * 2;
  int* row_cnt = (int*)w;             w += (size_t)NT * 4;
  int* cursor  = (int*)w;             w += (size_t)NT * 4;   // contiguous with row_cnt
  int* row_ptr = (int*)w;             w += (size_t)(NT + 1) * 4;
  int* tmp     = (int*)w;             w += (size_t)NT * 4;
  int* part    = (int*)w;             w += 512 * 4;
  int2* sedge  = (int2*)w;            w += (size_t)EDG * 8;

  // ---- sort edges by row (once; reused by both layers) ----
  hipMemsetAsync(row_cnt, 0, sizeof(int) * 2 * NT, stream);   // row_cnt + cursor
  hist_k<<<(E + 255) / 256, 256, 0, stream>>>(rows, row_cnt, E);
  scan1_k<<<NCH, 256, 0, stream>>>(row_cnt, tmp, part);
  scan2_k<<<1, 512, 0, stream>>>(part);
  scan3_k<<<NCH, 256, 0, stream>>>(tmp, part, row_ptr);
  scatter_k<<<(E + 255) / 256, 256, 0, stream>>>(rows, cols, vals, row_ptr,
                                                 cursor, sedge, E);

  // ---- hyper projections ----
  transp_both<<<2, 256, 0, stream>>>(u_hyp, i_hyp, uhT, ihT);
  proj_mfma<<<NBU_M + NBI_M, 256, 0, stream>>>(u_emb, i_emb, uhT, ihT, uuH, iiH);

  for (int k = 0; k < 2; ++k) {
    float* G = OUT_G + (size_t)k * NT * DD;
    float* H = OUT_H + (size_t)k * NT * DD;
    const float* pu = k == 0 ? u_emb : prev;
    const float* pi = k == 0 ? i_emb : prev + (size_t)NU * DD;

    // tem = leaky(spmm(prev))
    spmm_row_k<<<NT / 4, 256, 0, stream>>>(row_ptr, sedge, pu, pi, G);

    // hgnn lat chain (users + items merged)
    hipMemsetAsync(latU, 0, sizeof(float) * 2 * 16384, stream);
    tn_both<<<NBU_TN + NBI_TN, 256, 0, stream>>>(uuH, iiH, pu, pi, latU, latI);
    vg1_k<<<32, 256, 0, stream>>>(Vm, latU, latI, lat2U, lat2I);
    vg2_k<<<32, 256, 0, stream>>>(Vm, lat2U, lat2I, latTu, latTi);

    // H = lrelu(A @ lat) with fused epilogue
    if (k == 0)
      hyp_mfma<0><<<NBU_M + NBI_M, 256, 0, stream>>>(
          uuH, iiH, latTu, latTi, G, prev, u_emb, i_emb, H, out);
    else
      hyp_mfma<1><<<NBU_M + NBI_M, 256, 0, stream>>>(
          uuH, iiH, latTu, latTi, G, prev, u_emb, i_emb, H, out);
  }
}